// Round 4
// baseline (92.398 us; speedup 1.0000x reference)
//
#include <hip/hip_runtime.h>

// LIF spiking-neuron forward. x: [B=32,C=128,T=16,H=32,W=32] fp32 -> spikes.
// One thread owns 4 contiguous spatial elements of one (b,c) and walks t
// (stride HW=1024 floats). Rolling depth-8 software pipeline: preload 8
// t-slices, then per step issue load t+8 and compute/store t. Keeps 8-9
// VMEM ops in flight per wave with <=64 VGPR so 8 waves/SIMD fit
// (vs 4 with the 16-deep preload). Nontemporal on both streams
// (touch-once). All xi[] indices are compile-time constants (full unroll)
// so the array lives in registers with dead-slot reuse.

typedef float vfloat4 __attribute__((ext_vector_type(4)));

constexpr float K_THRESH = 0.5f;
constexpr float K_BETA   = 0.75f;
constexpr int   K_T      = 16;
constexpr int   K_HW     = 32 * 32;   // 1024
constexpr int   K_DEPTH  = 8;         // preload distance

__global__ __launch_bounds__(256, 8)   // cap VGPR at 64 -> 8 waves/SIMD
void lif_fwd_kernel(const float* __restrict__ x, float* __restrict__ out) {
    const int tid = blockIdx.x * blockDim.x + threadIdx.x;
    const int bc  = tid >> 8;            // / 256 : which (b,c) plane
    const int s4  = (tid & 255) << 2;    // * 4   : starting spatial element
    const size_t base = (size_t)bc * (K_T * K_HW) + (size_t)s4;

    vfloat4 xi[K_T];

    // Prologue: 8 loads in flight.
#pragma unroll
    for (int t = 0; t < K_DEPTH; ++t) {
        xi[t] = __builtin_nontemporal_load(
            reinterpret_cast<const vfloat4*>(x + base + (size_t)t * K_HW));
    }

    float m0 = 0.0f, m1 = 0.0f, m2 = 0.0f, m3 = 0.0f;

#pragma unroll
    for (int t = 0; t < K_T; ++t) {
        // Keep the pipeline full: issue load t+8 before consuming t.
        if (t + K_DEPTH < K_T) {
            xi[t + K_DEPTH] = __builtin_nontemporal_load(
                reinterpret_cast<const vfloat4*>(
                    x + base + (size_t)(t + K_DEPTH) * K_HW));
        }

        vfloat4 s;
        // Separate mul/add (no FMA contraction) -> bit-identical to the
        // reference's mem*beta + x. Reset subtracts exactly 0.5.
        m0 = __fadd_rn(__fmul_rn(m0, K_BETA), xi[t].x);
        s.x = (m0 > K_THRESH) ? 1.0f : 0.0f;
        m0 = __fsub_rn(m0, __fmul_rn(s.x, K_THRESH));

        m1 = __fadd_rn(__fmul_rn(m1, K_BETA), xi[t].y);
        s.y = (m1 > K_THRESH) ? 1.0f : 0.0f;
        m1 = __fsub_rn(m1, __fmul_rn(s.y, K_THRESH));

        m2 = __fadd_rn(__fmul_rn(m2, K_BETA), xi[t].z);
        s.z = (m2 > K_THRESH) ? 1.0f : 0.0f;
        m2 = __fsub_rn(m2, __fmul_rn(s.z, K_THRESH));

        m3 = __fadd_rn(__fmul_rn(m3, K_BETA), xi[t].w);
        s.w = (m3 > K_THRESH) ? 1.0f : 0.0f;
        m3 = __fsub_rn(m3, __fmul_rn(s.w, K_THRESH));

        __builtin_nontemporal_store(
            s, reinterpret_cast<vfloat4*>(out + base + (size_t)t * K_HW));
    }
}

extern "C" void kernel_launch(void* const* d_in, const int* in_sizes, int n_in,
                              void* d_out, int out_size, void* d_ws, size_t ws_size,
                              hipStream_t stream) {
    const float* x   = (const float*)d_in[0];
    float*       out = (float*)d_out;

    const int total   = in_sizes[0];            // 67,108,864 elements
    const int threads = total / (K_T * 4);      // 1,048,576 threads
    const int block   = 256;
    const int grid    = threads / block;        // 4096 blocks

    lif_fwd_kernel<<<grid, block, 0, stream>>>(x, out);
}